// Round 6
// baseline (134.142 us; speedup 1.0000x reference)
//
#include <hip/hip_runtime.h>
#include <hip/hip_fp16.h>
#include <math.h>
#include <limits.h>

#define NEGV (-1e30f)

constexpr int B = 512, T = 512, C = 128, L = 64;
constexpr int BLANK = C - 1;      // 127
constexpr float INV_LN2 = 1.44269504088896f;
constexpr float LN2 = 0.69314718055995f;
constexpr int PITCH = 66;         // halves per LDS row in rowstats transpose

typedef unsigned long long u64;

// ---------------------------------------------------------------------------
// DPP / lane helpers
// ---------------------------------------------------------------------------
__device__ __forceinline__ float dpp_shr1_f(float x, float old) {
  int r = __builtin_amdgcn_update_dpp(__float_as_int(old), __float_as_int(x),
                                      0x138, 0xf, 0xf, false);  // wave_shr:1
  return __int_as_float(r);
}
__device__ __forceinline__ float scan_max64(float x) {
  const int NI = (int)0xff800000;  // -inf
  int t;
  t = __builtin_amdgcn_update_dpp(NI, __float_as_int(x), 0x111, 0xf, 0xf, false);
  x = fmaxf(x, __int_as_float(t));
  t = __builtin_amdgcn_update_dpp(NI, __float_as_int(x), 0x112, 0xf, 0xf, false);
  x = fmaxf(x, __int_as_float(t));
  t = __builtin_amdgcn_update_dpp(NI, __float_as_int(x), 0x114, 0xf, 0xf, false);
  x = fmaxf(x, __int_as_float(t));
  t = __builtin_amdgcn_update_dpp(NI, __float_as_int(x), 0x118, 0xf, 0xf, false);
  x = fmaxf(x, __int_as_float(t));
  t = __builtin_amdgcn_update_dpp(NI, __float_as_int(x), 0x142, 0xa, 0xf, false);
  x = fmaxf(x, __int_as_float(t));
  t = __builtin_amdgcn_update_dpp(NI, __float_as_int(x), 0x143, 0xc, 0xf, false);
  x = fmaxf(x, __int_as_float(t));
  return x;  // lane63 = wave max
}
__device__ __forceinline__ float scan_add64(float x) {
  int t;
  t = __builtin_amdgcn_update_dpp(0, __float_as_int(x), 0x111, 0xf, 0xf, false);
  x += __int_as_float(t);
  t = __builtin_amdgcn_update_dpp(0, __float_as_int(x), 0x112, 0xf, 0xf, false);
  x += __int_as_float(t);
  t = __builtin_amdgcn_update_dpp(0, __float_as_int(x), 0x114, 0xf, 0xf, false);
  x += __int_as_float(t);
  t = __builtin_amdgcn_update_dpp(0, __float_as_int(x), 0x118, 0xf, 0xf, false);
  x += __int_as_float(t);
  t = __builtin_amdgcn_update_dpp(0, __float_as_int(x), 0x142, 0xa, 0xf, false);
  x += __int_as_float(t);
  t = __builtin_amdgcn_update_dpp(0, __float_as_int(x), 0x143, 0xc, 0xf, false);
  x += __int_as_float(t);
  return x;  // lane63 = wave sum
}
__device__ __forceinline__ float readlane63(float x) {
  return __int_as_float(__builtin_amdgcn_readlane(__float_as_int(x), 63));
}

// ---------------------------------------------------------------------------
// K1: per-(b,t) row stats; writes lp_lab TRANSPOSED [b][j][t] via LDS
// transpose. pred as uchar. Block = 256 threads = (b, 64 consecutive t).
// ---------------------------------------------------------------------------
__global__ __launch_bounds__(256) void rowstats_kernel(
    const float* __restrict__ logits, const int* __restrict__ labels,
    __half* __restrict__ lp_lab, float* __restrict__ lp_bl,
    unsigned char* __restrict__ predc) {
  __shared__ __half slp[64 * PITCH];
  int b = blockIdx.x >> 3;
  int t0 = (blockIdx.x & 7) << 6;
  int w = threadIdx.x >> 6;
  int lane = threadIdx.x & 63;
  int lab = labels[((size_t)b << 6) + lane];
  for (int i = 0; i < 16; ++i) {
    int t = t0 + w * 16 + i;
    const float* rp = logits + (size_t)(b * T + t) * C;
    float v1 = rp[lane];
    float v2 = rp[lane + 64];
    float m = readlane63(scan_max64(fmaxf(v1, v2)));
    unsigned long long b1 = __ballot(v1 == m);
    unsigned long long b2 = __ballot(v2 == m);
    int idx = b1 ? (__ffsll(b1) - 1) : (64 + __ffsll(b2) - 1);
    float s = __builtin_amdgcn_exp2f((v1 - m) * INV_LN2) +
              __builtin_amdgcn_exp2f((v2 - m) * INV_LN2);
    float l2t = __builtin_amdgcn_logf(readlane63(scan_add64(s)));
    float g1 = __shfl(v1, lab & 63);
    float g2 = __shfl(v2, lab & 63);
    float gv = (lab < 64) ? g1 : g2;
    slp[lane * PITCH + (t - t0)] = __float2half((gv - m) * INV_LN2 - l2t);
    if (lane == 63) lp_bl[b * T + t] = (v2 - m) * INV_LN2 - l2t;
    if (lane == 0) predc[b * T + t] = (unsigned char)idx;
  }
  __syncthreads();
  // writeout: thread k -> (j = k/4, quarter q = k%4): 32B of row j
  int j = threadIdx.x >> 2, q = threadIdx.x & 3;
  unsigned wbuf[8];
#pragma unroll
  for (int wd = 0; wd < 8; ++wd)
    wbuf[wd] = ((const unsigned*)slp)[j * (PITCH / 2) + q * 8 + wd];
  uint4 o0 = make_uint4(wbuf[0], wbuf[1], wbuf[2], wbuf[3]);
  uint4 o1 = make_uint4(wbuf[4], wbuf[5], wbuf[6], wbuf[7]);
  uint4* dst = (uint4*)(lp_lab + ((size_t)((b << 6) + j)) * T + t0 + q * 16);
  dst[0] = o0;
  dst[1] = o1;
}

// ---------------------------------------------------------------------------
// CTC alpha step, log2 domain. Lane j holds states {2j,2j+1}; aL = state 128.
// ---------------------------------------------------------------------------
__device__ __forceinline__ float lse2_2(float a, float b) {
  float m = fmaxf(a, b);
  float d = fminf(a, b) - m;
  return m + __builtin_amdgcn_logf(1.0f + __builtin_amdgcn_exp2f(d));
}
__device__ __forceinline__ void ctc_step(float lpl, float lpb, bool skip_ok,
                                         bool needL,
                                         float& aE, float& aO, float& aL) {
  float pO = dpp_shr1_f(aO, NEGV);   // alpha[2j-1]
  float pE = dpp_shr1_f(aE, NEGV);   // alpha[2j-2]
  float a3 = skip_ok ? pE : NEGV;
  float nE = lse2_2(aE, pO) + lpb;   // even state 2j (blank)
  float mO = fmaxf(fmaxf(aO, aE), a3);
  float sO = __builtin_amdgcn_exp2f(aO - mO) + __builtin_amdgcn_exp2f(aE - mO)
           + __builtin_amdgcn_exp2f(a3 - mO);
  float nO = mO + __builtin_amdgcn_logf(sO) + lpl;  // odd state 2j+1
  float nL = lse2_2(aL, aO) + lpb;                  // state 128 (tail blank)
  aL = needL ? nL : aL;
  aE = nE; aO = nO;
}

// extract half #k (0..15) from 2x uint4 (k compile-time constant)
__device__ __forceinline__ float geth(const uint4 (&buf)[2], int k) {
  const uint4& v = buf[k >> 3];
  int c2 = (k >> 1) & 3;
  unsigned comp = (c2 == 0) ? v.x : (c2 == 1) ? v.y : (c2 == 2) ? v.z : v.w;
  unsigned hs = (k & 1) ? (comp >> 16) : (comp & 0xffffu);
  unsigned short us = (unsigned short)hs;
  __half h;
  __builtin_memcpy(&h, &us, 2);
  return __half2float(h);
}
// extract byte #k (0..15) from uint4 (k compile-time constant)
__device__ __forceinline__ int getb(const uint4& v, int k) {
  int c4 = k >> 2;
  unsigned comp = (c4 == 0) ? v.x : (c4 == 1) ? v.y : (c4 == 2) ? v.z : v.w;
  return (int)((comp >> (8 * (k & 3))) & 0xffu);
}

// ---------------------------------------------------------------------------
// K2 fused: blocks [0,B) = CTC (wave/sample, CH=16 double-buffered chunks);
// blocks [B,B+8) = Myers bit-parallel edit distance (LANE = sample).
// ---------------------------------------------------------------------------
__global__ __launch_bounds__(64, 1) void dp_kernel(
    const __half* __restrict__ lp_lab, const float* __restrict__ lp_bl,
    const unsigned char* __restrict__ predc, const int* __restrict__ labels,
    const int* __restrict__ label_len, const int* __restrict__ logit_len,
    float* __restrict__ loss_b, float* __restrict__ ler_b) {
  __shared__ u64 peq[127 * 64];   // Myers Peq table, column = lane's sample
  int lane = threadIdx.x;
  if (blockIdx.x < (unsigned)B) {
    // ---------------- CTC path ----------------
    int b = blockIdx.x;
    int tl = logit_len[b];
    int ll = label_len[b];
    bool needL = (ll == L);
    int lab = labels[((size_t)b << 6) + lane];
    int labp = __shfl_up(lab, 1);
    bool skip_ok = (lane > 0) && (lab != labp);
    const __half* lpl_h = lp_lab + ((size_t)((b << 6) + lane)) * T;
    const float* lpbb = lp_bl + (size_t)b * T;
    float aE, aO, aL = NEGV;

    if (tl == T) {
      const uint4* lpl4 = (const uint4*)lpl_h;
      uint4 Abuf[2], Bbuf[2];
      float sA[16], sB[16];
      Abuf[0] = lpl4[0]; Abuf[1] = lpl4[1];
#pragma unroll
      for (int r = 0; r < 16; ++r) sA[r] = lpbb[r];
      Bbuf[0] = lpl4[2]; Bbuf[1] = lpl4[3];
#pragma unroll
      for (int r = 0; r < 16; ++r) sB[r] = lpbb[16 + r];
      __builtin_amdgcn_sched_barrier(0);

      aE = (lane == 0) ? sA[0] : NEGV;        // s=0: blank at t=0
      aO = (lane == 0) ? geth(Abuf, 0) : NEGV; // s=1: labels[0] at t=0
#pragma unroll
      for (int k = 1; k < 16; ++k)
        ctc_step(geth(Abuf, k), sA[k], skip_ok, needL, aE, aO, aL);

#pragma unroll 1
      for (int c = 1; c < 32; c += 2) {
        if (c + 1 < 32) {
          Abuf[0] = lpl4[(c + 1) * 2]; Abuf[1] = lpl4[(c + 1) * 2 + 1];
#pragma unroll
          for (int r = 0; r < 16; ++r) sA[r] = lpbb[(c + 1) * 16 + r];
        }
        __builtin_amdgcn_sched_barrier(0);
#pragma unroll
        for (int k = 0; k < 16; ++k)
          ctc_step(geth(Bbuf, k), sB[k], skip_ok, needL, aE, aO, aL);
        if (c + 2 < 32) {
          Bbuf[0] = lpl4[(c + 2) * 2]; Bbuf[1] = lpl4[(c + 2) * 2 + 1];
#pragma unroll
          for (int r = 0; r < 16; ++r) sB[r] = lpbb[(c + 2) * 16 + r];
        }
        __builtin_amdgcn_sched_barrier(0);
        if (c + 1 < 32) {
#pragma unroll
          for (int k = 0; k < 16; ++k)
            ctc_step(geth(Abuf, k), sA[k], skip_ok, needL, aE, aO, aL);
        }
      }
    } else {
      // general fallback (not exercised by this input shape)
      aE = (lane == 0) ? lpbb[0] : NEGV;
      aO = (lane == 0) ? __half2float(lpl_h[0]) : NEGV;
      for (int t = 1; t < tl; ++t)
        ctc_step(__half2float(lpl_h[t]), lpbb[t], skip_ok, needL, aE, aO, aL);
    }
    float e1 = needL ? __shfl(aL, 63) : __shfl(aE, ll);  // alpha[2*ll]
    float e2 = __shfl(aO, ll - 1);                       // alpha[2*ll-1]
    if (lane == 0) {
      float m = fmaxf(e1, e2);
      float r = m + __builtin_amdgcn_logf(__builtin_amdgcn_exp2f(e1 - m) +
                                          __builtin_amdgcn_exp2f(e2 - m));
      loss_b[b] = -r * LN2;
    }
  } else {
    // ---------------- Myers bit-parallel edit distance ----------------
    // lane = sample. Peq in LDS (own column, no barriers needed).
    int b = ((blockIdx.x - B) << 6) + lane;
    int tl = logit_len[b];
    int ll = label_len[b];
    // build Peq for this sample
    for (int c = 0; c < 127; ++c) peq[c * 64 + lane] = 0ULL;
    const int* lab = labels + ((size_t)b << 6);
    for (int j = 0; j < L; ++j)
      peq[lab[j] * 64 + lane] |= (1ULL << j);

    u64 Pv = ~0ULL, Mv = 0ULL;
    int score = ll;
    u64 mask = 1ULL << (ll - 1);
    int prevc = 255;
    const uint4* pb4 = (const uint4*)(predc + (size_t)b * T);

    uint4 PA = pb4[0], PB = pb4[1];
    __builtin_amdgcn_sched_barrier(0);
    u64 eqn = peq[min(getb(PA, 0), 126) * 64 + lane];  // prefetch step 0

#pragma unroll 1
    for (int g = 0; g < 32; ++g) {
      uint4 cur = (g & 1) ? PB : PA;
      // prefetch next chunk into the buffer just consumed
      if (g + 2 < 32) {
        if (g & 1) PB = pb4[g + 2]; else PA = pb4[g + 2];
      }
      int nb0 = (g + 1 < 32) ? ((g & 1) ? getb(PA, 0) : getb(PB, 0)) : 0;
#pragma unroll
      for (int k = 0; k < 16; ++k) {
        int t = g * 16 + k;
        int cc = getb(cur, k);
        u64 eq = eqn;
        int cn = (k < 15) ? getb(cur, k + 1) : nb0;
        eqn = peq[min(cn, 126) * 64 + lane];           // prefetch next step
        bool keep = (cc != BLANK) && (cc != prevc) && (t < tl);
        u64 Xv = eq | Mv;
        u64 Xh = (((eq & Pv) + Pv) ^ Pv) | eq;
        u64 Ph = Mv | ~(Xh | Pv);
        u64 Mh = Pv & Xh;
        int up = ((Ph & mask) != 0) ? 1 : 0;
        int dn = ((Mh & mask) != 0) ? 1 : 0;
        score += keep ? (up - dn) : 0;
        Ph = (Ph << 1) | 1ULL;
        Mh <<= 1;
        u64 nPv = Mh | ~(Xv | Ph);
        u64 nMv = Ph & Xv;
        Pv = keep ? nPv : Pv;
        Mv = keep ? nMv : Mv;
        prevc = cc;
      }
    }
    ler_b[b] = (float)score / (float)ll;
  }
}

// ---------------------------------------------------------------------------
// K3: deterministic final mean over B for loss and ler.
// ---------------------------------------------------------------------------
__global__ __launch_bounds__(512) void reduce_kernel(
    const float* __restrict__ loss_b, const float* __restrict__ ler_b,
    float* __restrict__ out) {
  __shared__ float sl[512];
  __shared__ float sr[512];
  int tid = threadIdx.x;
  sl[tid] = loss_b[tid];
  sr[tid] = ler_b[tid];
  __syncthreads();
  for (int off = 256; off; off >>= 1) {
    if (tid < off) { sl[tid] += sl[tid + off]; sr[tid] += sr[tid + off]; }
    __syncthreads();
  }
  if (tid == 0) {
    out[0] = sl[0] / (float)B;
    out[1] = sr[0] / (float)B;
  }
}

extern "C" void kernel_launch(void* const* d_in, const int* in_sizes, int n_in,
                              void* d_out, int out_size, void* d_ws, size_t ws_size,
                              hipStream_t stream) {
  const int*   labels    = (const int*)d_in[0];
  const float* logits    = (const float*)d_in[1];
  const int*   label_len = (const int*)d_in[2];
  const int*   logit_len = (const int*)d_in[3];
  float* out = (float*)d_out;

  char* ws = (char*)d_ws;
  __half* lp_lab = (__half*)ws;                                  // B*64*T f16 = 32 MB (transposed)
  float*  lp_bl  = (float*)(ws + (size_t)B * T * 64 * 2);        // B*T f32   =  1 MB
  unsigned char* predc = (unsigned char*)(ws + (size_t)B * T * 64 * 2 + (size_t)B * T * 4);
  float*  loss_b = (float*)(ws + (size_t)B * T * 64 * 2 + (size_t)B * T * 4 + (size_t)B * T);
  float*  ler_b  = loss_b + B;

  rowstats_kernel<<<B * (T / 64), 256, 0, stream>>>(logits, labels, lp_lab, lp_bl, predc);
  dp_kernel<<<B + 8, 64, 0, stream>>>(lp_lab, lp_bl, predc, labels, label_len,
                                      logit_len, loss_b, ler_b);
  reduce_kernel<<<1, 512, 0, stream>>>(loss_b, ler_b, out);
}

// Round 9
// 112.441 us; speedup vs baseline: 1.1930x; 1.1930x over previous
//
#include <hip/hip_runtime.h>
#include <hip/hip_fp16.h>
#include <math.h>

#define NEGV (-1e30f)
typedef unsigned long long u64;

constexpr int B = 512, T = 512, C = 128, L = 64;
constexpr int BLANK = C - 1;      // 127
constexpr float INV_LN2 = 1.44269504088896f;
constexpr float LN2 = 0.69314718055995f;

// ---------------------------------------------------------------------------
// async global->LDS (LDS dest = uniform base + lane*size; global src per-lane)
// ---------------------------------------------------------------------------
typedef const __attribute__((address_space(1))) void* gas_p;
typedef __attribute__((address_space(3))) void* las_p;
__device__ __forceinline__ void gload_lds16(const void* g, void* l) {
  __builtin_amdgcn_global_load_lds((gas_p)g, (las_p)l, 16, 0, 0);
}
__device__ __forceinline__ void gload_lds4(const void* g, void* l) {
  __builtin_amdgcn_global_load_lds((gas_p)g, (las_p)l, 4, 0, 0);
}
// deterministic full drain of the vmem queue (single-wave blocks: no barrier)
#define WAIT_VM0() do { \
  asm volatile("s_waitcnt vmcnt(0)" ::: "memory"); \
  __builtin_amdgcn_sched_barrier(0); } while (0)

// ---------------------------------------------------------------------------
// DPP / lane helpers
// ---------------------------------------------------------------------------
__device__ __forceinline__ float dpp_shr1_f(float x, float old) {
  int r = __builtin_amdgcn_update_dpp(__float_as_int(old), __float_as_int(x),
                                      0x138, 0xf, 0xf, false);  // wave_shr:1
  return __int_as_float(r);
}
__device__ __forceinline__ float scan_max64(float x) {
  const int NI = (int)0xff800000;  // -inf
  int t;
  t = __builtin_amdgcn_update_dpp(NI, __float_as_int(x), 0x111, 0xf, 0xf, false);
  x = fmaxf(x, __int_as_float(t));
  t = __builtin_amdgcn_update_dpp(NI, __float_as_int(x), 0x112, 0xf, 0xf, false);
  x = fmaxf(x, __int_as_float(t));
  t = __builtin_amdgcn_update_dpp(NI, __float_as_int(x), 0x114, 0xf, 0xf, false);
  x = fmaxf(x, __int_as_float(t));
  t = __builtin_amdgcn_update_dpp(NI, __float_as_int(x), 0x118, 0xf, 0xf, false);
  x = fmaxf(x, __int_as_float(t));
  t = __builtin_amdgcn_update_dpp(NI, __float_as_int(x), 0x142, 0xa, 0xf, false);
  x = fmaxf(x, __int_as_float(t));
  t = __builtin_amdgcn_update_dpp(NI, __float_as_int(x), 0x143, 0xc, 0xf, false);
  x = fmaxf(x, __int_as_float(t));
  return x;  // lane63 = wave max
}
__device__ __forceinline__ float scan_add64(float x) {
  int t;
  t = __builtin_amdgcn_update_dpp(0, __float_as_int(x), 0x111, 0xf, 0xf, false);
  x += __int_as_float(t);
  t = __builtin_amdgcn_update_dpp(0, __float_as_int(x), 0x112, 0xf, 0xf, false);
  x += __int_as_float(t);
  t = __builtin_amdgcn_update_dpp(0, __float_as_int(x), 0x114, 0xf, 0xf, false);
  x += __int_as_float(t);
  t = __builtin_amdgcn_update_dpp(0, __float_as_int(x), 0x118, 0xf, 0xf, false);
  x += __int_as_float(t);
  t = __builtin_amdgcn_update_dpp(0, __float_as_int(x), 0x142, 0xa, 0xf, false);
  x += __int_as_float(t);
  t = __builtin_amdgcn_update_dpp(0, __float_as_int(x), 0x143, 0xc, 0xf, false);
  x += __int_as_float(t);
  return x;  // lane63 = wave sum
}
__device__ __forceinline__ float readlane63(float x) {
  return __int_as_float(__builtin_amdgcn_readlane(__float_as_int(x), 63));
}

// ---------------------------------------------------------------------------
// K1: per-(b,t) row stats. Writes (log2 domain):
//   lp_lab[b][t][j] f16 (j-fast, coalesced), lp_blh[b][t] f16,
//   predc[b][t] u8 argmax, eqm[b][t] u64 = ballot(labels[b][j]==pred)
// Grid: blockIdx = chunk*512 + b  (all chunks of sample b on XCD b%8).
// ---------------------------------------------------------------------------
__global__ __launch_bounds__(256) void rowstats_kernel(
    const float* __restrict__ logits, const int* __restrict__ labels,
    __half* __restrict__ lp_lab, __half* __restrict__ lp_blh,
    unsigned char* __restrict__ predc, u64* __restrict__ eqm) {
  int b = blockIdx.x & 511;
  int t0 = (blockIdx.x >> 9) << 6;
  int w = threadIdx.x >> 6;
  int lane = threadIdx.x & 63;
  int lab = labels[((size_t)b << 6) + lane];
  for (int i = 0; i < 16; ++i) {
    int t = t0 + w * 16 + i;
    const float* rp = logits + (size_t)(b * T + t) * C;
    float v1 = rp[lane];
    float v2 = rp[lane + 64];
    float m = readlane63(scan_max64(fmaxf(v1, v2)));
    unsigned long long b1 = __ballot(v1 == m);
    unsigned long long b2 = __ballot(v2 == m);
    int idx = b1 ? (__ffsll(b1) - 1) : (64 + __ffsll(b2) - 1);
    u64 eqmask = __ballot(lab == idx);
    float s = __builtin_amdgcn_exp2f((v1 - m) * INV_LN2) +
              __builtin_amdgcn_exp2f((v2 - m) * INV_LN2);
    float l2t = __builtin_amdgcn_logf(readlane63(scan_add64(s)));
    float g1 = __shfl(v1, lab & 63);
    float g2 = __shfl(v2, lab & 63);
    float gv = (lab < 64) ? g1 : g2;
    lp_lab[((size_t)(b * T + t)) * 64 + lane] =
        __float2half((gv - m) * INV_LN2 - l2t);
    if (lane == 63) lp_blh[b * T + t] = __float2half((v2 - m) * INV_LN2 - l2t);
    if (lane == 0) { predc[b * T + t] = (unsigned char)idx; eqm[b * T + t] = eqmask; }
  }
}

// ---------------------------------------------------------------------------
// CTC alpha step, log2 domain. Lane j holds states {2j,2j+1}; aL = state 128
// (lane63-meaningful), updated only when ll==L (wave-uniform branch).
// ---------------------------------------------------------------------------
__device__ __forceinline__ float lse2_2(float a, float b) {
  float m = fmaxf(a, b);
  float d = fminf(a, b) - m;
  return m + __builtin_amdgcn_logf(1.0f + __builtin_amdgcn_exp2f(d));
}
__device__ __forceinline__ void ctc_step(float lpl, float lpb, bool skip_ok,
                                         bool needL,
                                         float& aE, float& aO, float& aL) {
  float pO = dpp_shr1_f(aO, NEGV);   // alpha[2j-1]
  float pE = dpp_shr1_f(aE, NEGV);   // alpha[2j-2]
  float a3 = skip_ok ? pE : NEGV;
  float nE = lse2_2(aE, pO) + lpb;   // even state 2j (blank)
  float mO = fmaxf(fmaxf(aO, aE), a3);
  float sO = __builtin_amdgcn_exp2f(aO - mO) + __builtin_amdgcn_exp2f(aE - mO)
           + __builtin_amdgcn_exp2f(a3 - mO);
  float nO = mO + __builtin_amdgcn_logf(sO) + lpl;  // odd state 2j+1
  if (needL) aL = lse2_2(aL, aO) + lpb;             // state 128 (tail blank)
  aE = nE; aO = nO;
}

// Myers/Hyyrö bit-parallel Levenshtein step (lane = one sample; select-only).
__device__ __forceinline__ void ed_step(u64 eq, int cc, int shift, bool tok,
                                        u64& Pv, u64& Mv, int& score, int& prevc) {
  bool keep = (cc != BLANK) && (cc != prevc) && tok;
  u64 Xv = eq | Mv;
  u64 Xh = (((eq & Pv) + Pv) ^ Pv) | eq;
  u64 Ph = Mv | ~(Xh | Pv);
  u64 Mh = Pv & Xh;
  int d = (int)((Ph >> shift) & 1ULL) - (int)((Mh >> shift) & 1ULL);
  score += keep ? d : 0;
  Ph = (Ph << 1) | 1ULL;
  Mh <<= 1;
  u64 nPv = Mh | ~(Xv | Ph);
  u64 nMv = Ph & Xv;
  Pv = keep ? nPv : Pv;
  Mv = keep ? nMv : Mv;
  prevc = cc;
}

// ---------------------------------------------------------------------------
// K2 fused. Blocks [0,8): Myers edit distance (lane = sample, 32-t chunks
// staged to LDS). Blocks [8,8+B): CTC (wave = sample, 64-t chunks staged to
// LDS). Staging = async global_load_lds, double-buffered; the only wait is a
// full vmcnt(0) drain issued one compute phase (~3200 cyc) after the loads.
// LDS: max(CTC 2*8448, Myers 2*18432) = 36864 B -> 4 blocks/CU cap.
// ---------------------------------------------------------------------------
__global__ __launch_bounds__(64, 1) void dp_kernel(
    const __half* __restrict__ lp_lab, const __half* __restrict__ lp_blh,
    const unsigned char* __restrict__ predc, const u64* __restrict__ eqm,
    const int* __restrict__ labels, const int* __restrict__ label_len,
    const int* __restrict__ logit_len,
    float* __restrict__ loss_b, float* __restrict__ ler_b) {
  __shared__ char smem[36864];
  int lane = threadIdx.x;

  if (blockIdx.x >= 8) {
    // ---------------- CTC path ----------------
    int b = blockIdx.x - 8;
    int tl = logit_len[b];
    int ll = label_len[b];
    bool needL = (ll == L);
    int lab = labels[((size_t)b << 6) + lane];
    int labp = __shfl_up(lab, 1);
    bool skip_ok = (lane > 0) && (lab != labp);
    const char* srcL = (const char*)(lp_lab + (size_t)b * T * 64);
    const char* srcB = (const char*)(lp_blh + (size_t)b * T);
    float aE, aO, aL = NEGV;

    if (tl == T) {
      // stage chunk c (64 t) into slot s: lpl 8KB (8 issues) + lpb (1 issue)
      auto stage = [&](int c, int s) {
        char* Lb = smem + s * 8448;
#pragma unroll
        for (int k = 0; k < 8; ++k)
          gload_lds16(srcL + (size_t)c * 8192 + k * 1024 + lane * 16,
                      Lb + k * 1024);
        gload_lds4(srcB + (size_t)c * 128 + lane * 4, Lb + 8192);
      };
      stage(0, 0);
      WAIT_VM0();
      stage(1, 1);
      {  // chunk 0 (peeled for t=0 init)
        const __half* pl = (const __half*)(smem);
        const __half* pb = (const __half*)(smem + 8192);
        float l0 = __half2float(pl[lane]);
        float b0 = __half2float(pb[0]);
        aE = (lane == 0) ? b0 : NEGV;   // s=0: blank at t=0
        aO = (lane == 0) ? l0 : NEGV;   // s=1: labels[0] at t=0
        for (int k4 = 0; k4 < 4; ++k4) {
#pragma unroll
          for (int kk = 0; kk < 16; ++kk) {
            int k = k4 * 16 + kk;
            if (k == 0) continue;
            ctc_step(__half2float(pl[k * 64 + lane]), __half2float(pb[k]),
                     skip_ok, needL, aE, aO, aL);
          }
        }
      }
#pragma unroll 1
      for (int c = 1; c < 8; ++c) {
        int s = c & 1;
        WAIT_VM0();                       // chunk c (staged last phase) ready
        if (c < 7) stage(c + 1, s ^ 1);   // prefetch next into other slot
        const __half* pl = (const __half*)(smem + s * 8448);
        const __half* pb = (const __half*)(smem + s * 8448 + 8192);
        for (int k4 = 0; k4 < 4; ++k4) {
#pragma unroll
          for (int kk = 0; kk < 16; ++kk) {
            int k = k4 * 16 + kk;
            ctc_step(__half2float(pl[k * 64 + lane]), __half2float(pb[k]),
                     skip_ok, needL, aE, aO, aL);
          }
        }
      }
    } else {
      // general fallback (not exercised by this input shape)
      const __half* pl = (const __half*)srcL;
      const __half* pb = (const __half*)srcB;
      aE = (lane == 0) ? __half2float(pb[0]) : NEGV;
      aO = (lane == 0) ? __half2float(pl[lane]) : NEGV;
      for (int t = 1; t < tl; ++t)
        ctc_step(__half2float(pl[(size_t)t * 64 + lane]), __half2float(pb[t]),
                 skip_ok, needL, aE, aO, aL);
    }
    float e1 = needL ? __shfl(aL, 63) : __shfl(aE, ll);  // alpha[2*ll]
    float e2 = __shfl(aO, ll - 1);                       // alpha[2*ll-1]
    if (lane == 0) {
      float m = fmaxf(e1, e2);
      float r = m + __builtin_amdgcn_logf(__builtin_amdgcn_exp2f(e1 - m) +
                                          __builtin_amdgcn_exp2f(e2 - m));
      loss_b[b] = -r * LN2;
    }
  } else {
    // ---------------- Myers edit distance (lane = sample) ----------------
    int bb = (blockIdx.x << 6) + lane;
    int tl = logit_len[bb];
    int ll = label_len[bb];
    int shift = ll - 1;
    u64 Pv = ~0ULL, Mv = 0ULL;
    int score = ll;
    int prevc = 255;
    const char* eqB = (const char*)(eqm + (size_t)bb * T);   // per-lane base
    const char* pqB = (const char*)(predc + (size_t)bb * T); // per-lane base
    // stage chunk c (32 t) into slot s: eq 16 issues + pred 2 issues
    auto stage = [&](int c, int s) {
      char* Eb = smem + s * 18432;
#pragma unroll
      for (int k = 0; k < 16; ++k)
        gload_lds16(eqB + (size_t)c * 256 + k * 16, Eb + k * 1024);
#pragma unroll
      for (int k = 0; k < 2; ++k)
        gload_lds16(pqB + (size_t)c * 32 + k * 16, Eb + 16384 + k * 1024);
    };
    stage(0, 0);
    WAIT_VM0();
    stage(1, 1);
#pragma unroll 1
    for (int c = 0; c < 16; ++c) {
      int s = c & 1;
      if (c) {
        WAIT_VM0();                       // chunk c ready
        if (c < 15) stage(c + 1, s ^ 1);  // prefetch next
      }
      const u64* ep = (const u64*)(smem + s * 18432);
      const unsigned char* pp = (const unsigned char*)(smem + s * 18432 + 16384);
#pragma unroll
      for (int k = 0; k < 32; ++k) {
        u64 eq = ep[(k >> 1) * 128 + lane * 2 + (k & 1)];
        int cc = pp[(k >> 4) * 1024 + lane * 16 + (k & 15)];
        ed_step(eq, cc, shift, c * 32 + k < tl, Pv, Mv, score, prevc);
      }
    }
    ler_b[bb] = (float)score / (float)ll;
  }
}

// ---------------------------------------------------------------------------
// K3: deterministic final mean over B for loss and ler.
// ---------------------------------------------------------------------------
__global__ __launch_bounds__(512) void reduce_kernel(
    const float* __restrict__ loss_b, const float* __restrict__ ler_b,
    float* __restrict__ out) {
  __shared__ float sl[512];
  __shared__ float sr[512];
  int tid = threadIdx.x;
  sl[tid] = loss_b[tid];
  sr[tid] = ler_b[tid];
  __syncthreads();
  for (int off = 256; off; off >>= 1) {
    if (tid < off) { sl[tid] += sl[tid + off]; sr[tid] += sr[tid + off]; }
    __syncthreads();
  }
  if (tid == 0) {
    out[0] = sl[0] / (float)B;
    out[1] = sr[0] / (float)B;
  }
}

extern "C" void kernel_launch(void* const* d_in, const int* in_sizes, int n_in,
                              void* d_out, int out_size, void* d_ws, size_t ws_size,
                              hipStream_t stream) {
  const int*   labels    = (const int*)d_in[0];
  const float* logits    = (const float*)d_in[1];
  const int*   label_len = (const int*)d_in[2];
  const int*   logit_len = (const int*)d_in[3];
  float* out = (float*)d_out;

  char* ws = (char*)d_ws;
  const size_t OFF_BLH  = (size_t)B * T * 64 * 2;        // after 32MB lp_lab
  const size_t OFF_EQM  = OFF_BLH + (size_t)B * T * 2;   // after 0.5MB lp_blh
  const size_t OFF_PRED = OFF_EQM + (size_t)B * T * 8;   // after 2MB eqm
  const size_t OFF_RED  = OFF_PRED + (size_t)B * T;      // after 0.25MB predc
  __half* lp_lab = (__half*)ws;
  __half* lp_blh = (__half*)(ws + OFF_BLH);
  u64*    eqm    = (u64*)(ws + OFF_EQM);
  unsigned char* predc = (unsigned char*)(ws + OFF_PRED);
  float*  loss_b = (float*)(ws + OFF_RED);
  float*  ler_b  = loss_b + B;

  rowstats_kernel<<<B * (T / 64), 256, 0, stream>>>(logits, labels, lp_lab,
                                                    lp_blh, predc, eqm);
  dp_kernel<<<B + 8, 64, 0, stream>>>(lp_lab, lp_blh, predc, eqm, labels,
                                      label_len, logit_len, loss_b, ler_b);
  reduce_kernel<<<1, 512, 0, stream>>>(loss_b, ler_b, out);
}

// Round 10
// 91.844 us; speedup vs baseline: 1.4605x; 1.2243x over previous
//
#include <hip/hip_runtime.h>
#include <hip/hip_fp16.h>
#include <math.h>

#define NEGV (-1e30f)
typedef unsigned long long u64;

constexpr int B = 512, T = 512, C = 128, L = 64;
constexpr int BLANK = C - 1;      // 127
constexpr float INV_LN2 = 1.44269504088896f;
constexpr float LN2 = 0.69314718055995f;

// ---------------------------------------------------------------------------
// async global->LDS (LDS dest = uniform base + lane*size; global src per-lane)
// ---------------------------------------------------------------------------
typedef const __attribute__((address_space(1))) void* gas_p;
typedef __attribute__((address_space(3))) void* las_p;
__device__ __forceinline__ void gload_lds16(const void* g, void* l) {
  __builtin_amdgcn_global_load_lds((gas_p)g, (las_p)l, 16, 0, 0);
}
__device__ __forceinline__ void gload_lds4(const void* g, void* l) {
  __builtin_amdgcn_global_load_lds((gas_p)g, (las_p)l, 4, 0, 0);
}
// deterministic full drain of the vmem queue (single-wave blocks: no barrier)
#define WAIT_VM0() do { \
  asm volatile("s_waitcnt vmcnt(0)" ::: "memory"); \
  __builtin_amdgcn_sched_barrier(0); } while (0)

// ---------------------------------------------------------------------------
// DPP / lane helpers
// ---------------------------------------------------------------------------
__device__ __forceinline__ float dpp_shr1_f(float x, float old) {
  int r = __builtin_amdgcn_update_dpp(__float_as_int(old), __float_as_int(x),
                                      0x138, 0xf, 0xf, false);  // wave_shr:1
  return __int_as_float(r);
}
__device__ __forceinline__ float scan_max64(float x) {
  const int NI = (int)0xff800000;  // -inf
  int t;
  t = __builtin_amdgcn_update_dpp(NI, __float_as_int(x), 0x111, 0xf, 0xf, false);
  x = fmaxf(x, __int_as_float(t));
  t = __builtin_amdgcn_update_dpp(NI, __float_as_int(x), 0x112, 0xf, 0xf, false);
  x = fmaxf(x, __int_as_float(t));
  t = __builtin_amdgcn_update_dpp(NI, __float_as_int(x), 0x114, 0xf, 0xf, false);
  x = fmaxf(x, __int_as_float(t));
  t = __builtin_amdgcn_update_dpp(NI, __float_as_int(x), 0x118, 0xf, 0xf, false);
  x = fmaxf(x, __int_as_float(t));
  t = __builtin_amdgcn_update_dpp(NI, __float_as_int(x), 0x142, 0xa, 0xf, false);
  x = fmaxf(x, __int_as_float(t));
  t = __builtin_amdgcn_update_dpp(NI, __float_as_int(x), 0x143, 0xc, 0xf, false);
  x = fmaxf(x, __int_as_float(t));
  return x;  // lane63 = wave max
}
__device__ __forceinline__ float scan_add64(float x) {
  int t;
  t = __builtin_amdgcn_update_dpp(0, __float_as_int(x), 0x111, 0xf, 0xf, false);
  x += __int_as_float(t);
  t = __builtin_amdgcn_update_dpp(0, __float_as_int(x), 0x112, 0xf, 0xf, false);
  x += __int_as_float(t);
  t = __builtin_amdgcn_update_dpp(0, __float_as_int(x), 0x114, 0xf, 0xf, false);
  x += __int_as_float(t);
  t = __builtin_amdgcn_update_dpp(0, __float_as_int(x), 0x118, 0xf, 0xf, false);
  x += __int_as_float(t);
  t = __builtin_amdgcn_update_dpp(0, __float_as_int(x), 0x142, 0xa, 0xf, false);
  x += __int_as_float(t);
  t = __builtin_amdgcn_update_dpp(0, __float_as_int(x), 0x143, 0xc, 0xf, false);
  x += __int_as_float(t);
  return x;  // lane63 = wave sum
}
__device__ __forceinline__ float readlane63(float x) {
  return __int_as_float(__builtin_amdgcn_readlane(__float_as_int(x), 63));
}

// ---------------------------------------------------------------------------
// K1: per-(b,t) row stats. Writes (log2 domain):
//   lp_lab[b][t][j] f16 (j-fast, coalesced), lp_blh[b][t] f16,
//   predc[b][t] u8 argmax, eqm[b][t] u64 = ballot(labels[b][j]==pred)
// Grid: blockIdx = chunk*512 + b  (all chunks of sample b on XCD b%8).
// ---------------------------------------------------------------------------
__global__ __launch_bounds__(256) void rowstats_kernel(
    const float* __restrict__ logits, const int* __restrict__ labels,
    __half* __restrict__ lp_lab, __half* __restrict__ lp_blh,
    unsigned char* __restrict__ predc, u64* __restrict__ eqm) {
  int b = blockIdx.x & 511;
  int t0 = (blockIdx.x >> 9) << 6;
  int w = threadIdx.x >> 6;
  int lane = threadIdx.x & 63;
  int lab = labels[((size_t)b << 6) + lane];
  for (int i = 0; i < 16; ++i) {
    int t = t0 + w * 16 + i;
    const float* rp = logits + (size_t)(b * T + t) * C;
    float v1 = rp[lane];
    float v2 = rp[lane + 64];
    float m = readlane63(scan_max64(fmaxf(v1, v2)));
    unsigned long long b1 = __ballot(v1 == m);
    unsigned long long b2 = __ballot(v2 == m);
    int idx = b1 ? (__ffsll(b1) - 1) : (64 + __ffsll(b2) - 1);
    u64 eqmask = __ballot(lab == idx);
    float s = __builtin_amdgcn_exp2f((v1 - m) * INV_LN2) +
              __builtin_amdgcn_exp2f((v2 - m) * INV_LN2);
    float l2t = __builtin_amdgcn_logf(readlane63(scan_add64(s)));
    float g1 = __shfl(v1, lab & 63);
    float g2 = __shfl(v2, lab & 63);
    float gv = (lab < 64) ? g1 : g2;
    lp_lab[((size_t)(b * T + t)) * 64 + lane] =
        __float2half((gv - m) * INV_LN2 - l2t);
    if (lane == 63) lp_blh[b * T + t] = __float2half((v2 - m) * INV_LN2 - l2t);
    if (lane == 0) { predc[b * T + t] = (unsigned char)idx; eqm[b * T + t] = eqmask; }
  }
}

// ---------------------------------------------------------------------------
// CTC alpha step, log2 domain, BRANCHLESS. State layout: lane j holds
// {state 2j+1 (label j) = aO, state 2j+2 (blank) = aE}; state 0 is the
// scalar a0 (pure accumulation: a0 += lpb). State 128 = lane63's aE.
//   nO = LSE(aO, pE, skip? pO) + lpl   (pE = aE>>1 w/ lane0<-a0, pO = aO>>1)
//   nE = LSE(aE, aO) + lpb             (no cross-lane!)
// ---------------------------------------------------------------------------
__device__ __forceinline__ void ctc_step(float lpl, float lpb, bool skip_ok,
                                         float& aE, float& aO, float& a0) {
  float pE = dpp_shr1_f(aE, a0);     // alpha[2j]   (lane0: alpha[0]=a0)
  float pO = dpp_shr1_f(aO, NEGV);   // alpha[2j-1] (lane0: none)
  float a3 = skip_ok ? pO : NEGV;
  // odd state 2j+1: LSE3(aO, pE, a3) + lpl
  float mO = fmaxf(fmaxf(aO, pE), a3);
  float sO = __builtin_amdgcn_exp2f(aO - mO) + __builtin_amdgcn_exp2f(pE - mO)
           + __builtin_amdgcn_exp2f(a3 - mO);
  float nO = mO + __builtin_amdgcn_logf(sO) + lpl;
  // even state 2j+2: LSE2(aE, aO) + lpb
  float mE = fmaxf(aE, aO);
  float dE = -fabsf(aE - aO);
  float nE = mE + __builtin_amdgcn_logf(1.0f + __builtin_amdgcn_exp2f(dE)) + lpb;
  a0 += lpb;
  aE = nE; aO = nO;
}

// Myers/Hyyrö bit-parallel Levenshtein step (lane = one sample; select-only).
__device__ __forceinline__ void ed_step(u64 eq, int cc, int shift, bool tok,
                                        u64& Pv, u64& Mv, int& score, int& prevc) {
  bool keep = (cc != BLANK) && (cc != prevc) && tok;
  u64 Xv = eq | Mv;
  u64 Xh = (((eq & Pv) + Pv) ^ Pv) | eq;
  u64 Ph = Mv | ~(Xh | Pv);
  u64 Mh = Pv & Xh;
  int d = (int)((Ph >> shift) & 1ULL) - (int)((Mh >> shift) & 1ULL);
  score += keep ? d : 0;
  Ph = (Ph << 1) | 1ULL;
  Mh <<= 1;
  u64 nPv = Mh | ~(Xv | Ph);
  u64 nMv = Ph & Xv;
  Pv = keep ? nPv : Pv;
  Mv = keep ? nMv : Mv;
  prevc = cc;
}

// ---------------------------------------------------------------------------
// K2 fused. Blocks [0,8): Myers edit distance (lane = sample, 32-t chunks
// staged to LDS). Blocks [8,8+B): CTC (wave = sample, 64-t chunks staged to
// LDS). Staging = async global_load_lds, double-buffered; the only wait is a
// full vmcnt(0) drain issued one compute phase after the loads. CTC steps are
// branchless -> 16-step bodies are single basic blocks -> ds_reads hoist.
// LDS: max(CTC 2*8448, Myers 2*18432) = 36864 B.
// ---------------------------------------------------------------------------
__global__ __launch_bounds__(64, 1) void dp_kernel(
    const __half* __restrict__ lp_lab, const __half* __restrict__ lp_blh,
    const unsigned char* __restrict__ predc, const u64* __restrict__ eqm,
    const int* __restrict__ labels, const int* __restrict__ label_len,
    const int* __restrict__ logit_len,
    float* __restrict__ loss_b, float* __restrict__ ler_b) {
  __shared__ char smem[36864];
  int lane = threadIdx.x;

  if (blockIdx.x >= 8) {
    // ---------------- CTC path ----------------
    int b = blockIdx.x - 8;
    int tl = logit_len[b];
    int ll = label_len[b];
    int lab = labels[((size_t)b << 6) + lane];
    int labp = __shfl_up(lab, 1);
    bool skip_ok = (lane > 0) && (lab != labp);
    const char* srcL = (const char*)(lp_lab + (size_t)b * T * 64);
    const char* srcB = (const char*)(lp_blh + (size_t)b * T);
    float aE = NEGV, aO, a0;

    if (tl == T) {
      // stage chunk c (64 t) into slot s: lpl 8KB (8 issues) + lpb (1 issue)
      auto stage = [&](int c, int s) {
        char* Lb = smem + s * 8448;
#pragma unroll
        for (int k = 0; k < 8; ++k)
          gload_lds16(srcL + (size_t)c * 8192 + k * 1024 + lane * 16,
                      Lb + k * 1024);
        gload_lds4(srcB + (size_t)c * 128 + lane * 4, Lb + 8192);
      };
      stage(0, 0);
      WAIT_VM0();
      stage(1, 1);
      {  // chunk 0 (peeled for t=0 init)
        const __half* pl = (const __half*)(smem);
        const __half* pb = (const __half*)(smem + 8192);
        a0 = __half2float(pb[0]);               // alpha[0](0) = lp_blank
        aO = (lane == 0) ? __half2float(pl[lane]) : NEGV;  // alpha[1](0)
        for (int k4 = 0; k4 < 4; ++k4) {
#pragma unroll
          for (int kk = 0; kk < 16; ++kk) {
            int k = k4 * 16 + kk;
            if (k == 0) continue;
            ctc_step(__half2float(pl[k * 64 + lane]), __half2float(pb[k]),
                     skip_ok, aE, aO, a0);
          }
        }
      }
#pragma unroll 1
      for (int c = 1; c < 8; ++c) {
        int s = c & 1;
        WAIT_VM0();                       // chunk c (staged last phase) ready
        if (c < 7) stage(c + 1, s ^ 1);   // prefetch next into other slot
        const __half* pl = (const __half*)(smem + s * 8448);
        const __half* pb = (const __half*)(smem + s * 8448 + 8192);
        for (int k4 = 0; k4 < 4; ++k4) {
#pragma unroll
          for (int kk = 0; kk < 16; ++kk) {
            int k = k4 * 16 + kk;
            ctc_step(__half2float(pl[k * 64 + lane]), __half2float(pb[k]),
                     skip_ok, aE, aO, a0);
          }
        }
      }
    } else {
      // general fallback (not exercised by this input shape)
      const __half* pl = (const __half*)srcL;
      const __half* pb = (const __half*)srcB;
      a0 = __half2float(pb[0]);
      aO = (lane == 0) ? __half2float(pl[lane]) : NEGV;
      for (int t = 1; t < tl; ++t)
        ctc_step(__half2float(pl[(size_t)t * 64 + lane]), __half2float(pb[t]),
                 skip_ok, aE, aO, a0);
    }
    // alpha[2ll] = aE at lane ll-1; alpha[2ll-1] = aO at lane ll-1
    float e1 = __shfl(aE, ll - 1);
    float e2 = __shfl(aO, ll - 1);
    if (lane == 0) {
      float m = fmaxf(e1, e2);
      float r = m + __builtin_amdgcn_logf(__builtin_amdgcn_exp2f(e1 - m) +
                                          __builtin_amdgcn_exp2f(e2 - m));
      loss_b[b] = -r * LN2;
    }
  } else {
    // ---------------- Myers edit distance (lane = sample) ----------------
    int bb = (blockIdx.x << 6) + lane;
    int tl = logit_len[bb];
    int ll = label_len[bb];
    int shift = ll - 1;
    u64 Pv = ~0ULL, Mv = 0ULL;
    int score = ll;
    int prevc = 255;
    const char* eqB = (const char*)(eqm + (size_t)bb * T);   // per-lane base
    const char* pqB = (const char*)(predc + (size_t)bb * T); // per-lane base
    // stage chunk c (32 t) into slot s: eq 16 issues + pred 2 issues
    auto stage = [&](int c, int s) {
      char* Eb = smem + s * 18432;
#pragma unroll
      for (int k = 0; k < 16; ++k)
        gload_lds16(eqB + (size_t)c * 256 + k * 16, Eb + k * 1024);
#pragma unroll
      for (int k = 0; k < 2; ++k)
        gload_lds16(pqB + (size_t)c * 32 + k * 16, Eb + 16384 + k * 1024);
    };
    stage(0, 0);
    WAIT_VM0();
    stage(1, 1);
#pragma unroll 1
    for (int c = 0; c < 16; ++c) {
      int s = c & 1;
      if (c) {
        WAIT_VM0();                       // chunk c ready
        if (c < 15) stage(c + 1, s ^ 1);  // prefetch next
      }
      const u64* ep = (const u64*)(smem + s * 18432);
      const unsigned char* pp = (const unsigned char*)(smem + s * 18432 + 16384);
#pragma unroll
      for (int k = 0; k < 32; ++k) {
        u64 eq = ep[(k >> 1) * 128 + lane * 2 + (k & 1)];
        int cc = pp[(k >> 4) * 1024 + lane * 16 + (k & 15)];
        ed_step(eq, cc, shift, c * 32 + k < tl, Pv, Mv, score, prevc);
      }
    }
    ler_b[bb] = (float)score / (float)ll;
  }
}

// ---------------------------------------------------------------------------
// K3: deterministic final mean over B for loss and ler.
// ---------------------------------------------------------------------------
__global__ __launch_bounds__(512) void reduce_kernel(
    const float* __restrict__ loss_b, const float* __restrict__ ler_b,
    float* __restrict__ out) {
  __shared__ float sl[512];
  __shared__ float sr[512];
  int tid = threadIdx.x;
  sl[tid] = loss_b[tid];
  sr[tid] = ler_b[tid];
  __syncthreads();
  for (int off = 256; off; off >>= 1) {
    if (tid < off) { sl[tid] += sl[tid + off]; sr[tid] += sr[tid + off]; }
    __syncthreads();
  }
  if (tid == 0) {
    out[0] = sl[0] / (float)B;
    out[1] = sr[0] / (float)B;
  }
}

extern "C" void kernel_launch(void* const* d_in, const int* in_sizes, int n_in,
                              void* d_out, int out_size, void* d_ws, size_t ws_size,
                              hipStream_t stream) {
  const int*   labels    = (const int*)d_in[0];
  const float* logits    = (const float*)d_in[1];
  const int*   label_len = (const int*)d_in[2];
  const int*   logit_len = (const int*)d_in[3];
  float* out = (float*)d_out;

  char* ws = (char*)d_ws;
  const size_t OFF_BLH  = (size_t)B * T * 64 * 2;        // after 32MB lp_lab
  const size_t OFF_EQM  = OFF_BLH + (size_t)B * T * 2;   // after 0.5MB lp_blh
  const size_t OFF_PRED = OFF_EQM + (size_t)B * T * 8;   // after 2MB eqm
  const size_t OFF_RED  = OFF_PRED + (size_t)B * T;      // after 0.25MB predc
  __half* lp_lab = (__half*)ws;
  __half* lp_blh = (__half*)(ws + OFF_BLH);
  u64*    eqm    = (u64*)(ws + OFF_EQM);
  unsigned char* predc = (unsigned char*)(ws + OFF_PRED);
  float*  loss_b = (float*)(ws + OFF_RED);
  float*  ler_b  = loss_b + B;

  rowstats_kernel<<<B * (T / 64), 256, 0, stream>>>(logits, labels, lp_lab,
                                                    lp_blh, predc, eqm);
  dp_kernel<<<B + 8, 64, 0, stream>>>(lp_lab, lp_blh, predc, eqm, labels,
                                      label_len, logit_len, loss_b, ler_b);
  reduce_kernel<<<1, 512, 0, stream>>>(loss_b, ler_b, out);
}